// Round 10
// baseline (203.244 us; speedup 1.0000x reference)
//
#include <hip/hip_runtime.h>
#include <math.h>

#define B_   128
#define L_   128
#define E_   300
#define P_   50
#define FN_  256
#define H2_  100
#define LAB_ 19

typedef unsigned short ushort_t;
typedef __attribute__((ext_vector_type(8))) short bf16x8;
typedef __attribute__((ext_vector_type(4))) float f32x4;

// ---- aligned folded geometry ----
// we rows padded 300->304 elems (608B, 16B-aligned); pos rows 100->104 (208B).
// word K = (k+2)*304 pad64 ; pos K = k*104 pad64 ; corr K = 3*304 pad64 = 960
#define SW 304
#define SP 104
#define WE_SLAB  40960      // per-b we elems (130*304=39520 + zero tail; max read 40783)
#define POS_SLAB 14336      // per-b pos elems (128*104=13312 + zero tail; max read 13783)
#define KW0 1536
#define KW1 1856
#define KW2 2176
#define KP0 320
#define KP1 448
#define KP2 576
#define KC  960

#define N_WE   (B_ * WE_SLAB)                 // 5,242,880
#define N_POSF (B_ * POS_SLAB)                // 1,835,008
#define N_WFW  (FN_ * (KW0 + KW1 + KW2))      // 1,425,408
#define N_WFP  (FN_ * (KP0 + KP1 + KP2))      // 344,064
#define N_CORR (3 * FN_ * KC)                 // 737,280

#define WEB2  (N_WE / 2048)                   // 2560
#define POSB2 (N_POSF / 2048)                 // 896
#define WFWB2 (N_WFW / 2048)                  // 696
#define WFPB2 (N_WFP / 2048)                  // 168
#define CORB2 (N_CORR / 2048)                 // 360
#define SETUP_BLOCKS (WEB2 + POSB2 + WFWB2 + WFPB2 + CORB2)

__device__ __forceinline__ ushort_t f2bf(float x) {
    unsigned u = __float_as_uint(x);
    u += 0x7FFFu + ((u >> 16) & 1u);
    return (ushort_t)(u >> 16);
}
__device__ __forceinline__ float bf2f(ushort_t u) {
    return __uint_as_float((unsigned)u << 16);
}

__device__ __forceinline__ void gld_lds16(const void* g, void* lds_uniform) {
    __builtin_amdgcn_global_load_lds(
        (const __attribute__((address_space(1))) void*)g,
        (__attribute__((address_space(3))) void*)lds_uniform,
        16, 0, 0);
}

#define MEMFENCE asm volatile("" ::: "memory")
#define WAITV12  asm volatile("s_waitcnt vmcnt(12)" ::: "memory")

// ================= setup: x8-vectorized builds (aligned-stride layouts) ======
__global__ __launch_bounds__(256) void setup_kernel(
    const int* __restrict__ inputs, const int* __restrict__ p1, const int* __restrict__ p2,
    const float* __restrict__ emb, const float* __restrict__ pos1, const float* __restrict__ pos2,
    const float* __restrict__ w3, const float* __restrict__ w4, const float* __restrict__ w5,
    ushort_t* __restrict__ we_flat, ushort_t* __restrict__ posflat,
    ushort_t* __restrict__ wfw, ushort_t* __restrict__ wfp, ushort_t* __restrict__ corrw)
{
    int e = (blockIdx.x * 256 + threadIdx.x) * 8;
    bf16x8 v = {0, 0, 0, 0, 0, 0, 0, 0};

    if (e < N_WE) {                          // ---- we_flat, rows stride 304
        int b = e / WE_SLAB, rem = e - b * WE_SLAB;
        if (rem < 130 * SW) {
            int row = rem / SW, c0 = rem - row * SW;
            int tok = (row == 0 || row == 129) ? 0 : inputs[b * L_ + row - 1];
            const float* er = emb + (size_t)tok * 300;
#pragma unroll
            for (int m = 0; m < 8; ++m) {
                int c = c0 + m;
                v[m] = (c < 300) ? (short)f2bf(er[c]) : (short)0;
            }
        }
        *(bf16x8*)(we_flat + e) = v;
        return;
    }
    e -= N_WE;
    if (e < N_POSF) {                        // ---- posflat, rows stride 104
        int b = e / POS_SLAB, rem = e - b * POS_SLAB;
        if (rem < 128 * SP) {
            int row = rem / SP, c0 = rem - row * SP;
            int pp1 = p1[b * L_ + row], pp2 = p2[b * L_ + row];
#pragma unroll
            for (int m = 0; m < 8; ++m) {
                int c = c0 + m;
                float x = (c < 50) ? pos1[(size_t)pp1 * 50 + c]
                        : (c < 100) ? pos2[(size_t)pp2 * 50 + (c - 50)] : 0.f;
                v[m] = (short)f2bf(x);
            }
        }
        *(bf16x8*)(posflat + e) = v;
        return;
    }
    e -= N_POSF;
    if (e < N_WFW) {                         // ---- folded word weights, kk = m*304+c
        int conv, k, kwp;
        const float* w;
        int seg = e;
        if (seg < FN_ * KW0)                     { conv = 0; k = 3; kwp = KW0; w = w3; }
        else if ((seg -= FN_ * KW0) < FN_ * KW1) { conv = 1; k = 4; kwp = KW1; w = w4; }
        else                      { seg -= FN_ * KW1; conv = 2; k = 5; kwp = KW2; w = w5; }
        int f = seg / kwp, kk0 = seg - f * kwp;
#pragma unroll
        for (int m8 = 0; m8 < 8; ++m8) {
            int kk = kk0 + m8;
            int mr = kk / SW, c = kk - mr * SW;
            float s = 0.f;
            if (mr < k + 2 && c < 300) {
                int jlo = (mr - 2 < 0) ? 0 : mr - 2;
                int jhi = (mr < k - 1) ? mr : k - 1;
                for (int j = jlo; j <= jhi; ++j)
                    s += w[(size_t)f * (k * 1000) + j * 1000 + (mr - j) * 300 + c];
            }
            v[m8] = (short)f2bf(s);
        }
        *(bf16x8*)(wfw + e) = v;
        return;
    }
    e -= N_WFW;
    if (e < N_WFP) {                         // ---- pos weights, kk = j*104+c
        int conv, k, kpp;
        const float* w;
        int seg = e;
        if (seg < FN_ * KP0)                     { conv = 0; k = 3; kpp = KP0; w = w3; }
        else if ((seg -= FN_ * KP0) < FN_ * KP1) { conv = 1; k = 4; kpp = KP1; w = w4; }
        else                      { seg -= FN_ * KP1; conv = 2; k = 5; kpp = KP2; w = w5; }
        int f = seg / kpp, kk0 = seg - f * kpp;
#pragma unroll
        for (int m8 = 0; m8 < 8; ++m8) {
            int kk = kk0 + m8;
            int j = kk / SP, c = kk - j * SP;
            float x = (j < k && c < 100) ? w[(size_t)f * (k * 1000) + j * 1000 + 900 + c] : 0.f;
            v[m8] = (short)f2bf(x);
        }
        *(bf16x8*)(wfp + e) = v;
        return;
    }
    e -= N_WFP;
    {                                        // ---- corr weights, kk = m*304+c -> w[f,0,m*300+c]
        int conv = e / (FN_ * KC), seg = e - conv * (FN_ * KC);
        int k = 3 + conv;
        const float* w = (conv == 0) ? w3 : (conv == 1) ? w4 : w5;
        int f = seg / KC, kk0 = seg - f * KC;
#pragma unroll
        for (int m8 = 0; m8 < 8; ++m8) {
            int kk = kk0 + m8;
            int mr = kk / SW, c = kk - mr * SW;
            v[m8] = (mr < 3 && c < 300) ? (short)f2bf(w[(size_t)f * (k * 1000) + mr * 300 + c])
                                        : (short)0;
        }
        *(bf16x8*)(corrw + e) = v;
    }
}

// ===== conv: grid (b, conv, nhalf), conv = 2 - y (longest first).
// A-frags: aligned dwordx4 direct from global, REGISTER double-buffered
// (issue-early/consume-late). B: 3-buffer LDS, swizzled, ONE barrier per
// k-tile, counted vmcnt(12). 4 waves 2m x 2n, wave tile 64x64.
__global__ __launch_bounds__(256, 2) void conv_fold(
    const ushort_t* __restrict__ we_flat, const ushort_t* __restrict__ posflat,
    const ushort_t* __restrict__ wfw, const ushort_t* __restrict__ wfp,
    const ushort_t* __restrict__ corrw,
    const float* __restrict__ cb3, const float* __restrict__ cb4, const float* __restrict__ cb5,
    float* __restrict__ sf)
{
    __shared__ ushort_t sB[3][8192];          // 3 x 16 KB (chunk-swizzled)
    __shared__ float corr_lds[128];
    __shared__ float red[2][128];

    int b    = blockIdx.x;
    int conv = 2 - blockIdx.y;                // 2,1,0: longest groups dispatched first
    int n0c  = blockIdx.z << 7;

    const int ntw = (conv == 0) ? KW0 / 64 : (conv == 1) ? KW1 / 64 : KW2 / 64;
    const int ntp = (conv == 0) ? KP0 / 64 : (conv == 1) ? KP1 / 64 : KP2 / 64;
    const int nt  = ntw + ntp;
    const size_t kwB = (size_t)(ntw * 64) * 2;     // B row stride, bytes (16B-mult)
    const size_t kpB = (size_t)(ntp * 64) * 2;
    const size_t wfwoff = (conv == 0) ? 0 : (conv == 1) ? (size_t)FN_ * KW0 : (size_t)FN_ * (KW0 + KW1);
    const size_t wfpoff = (conv == 0) ? 0 : (conv == 1) ? (size_t)FN_ * KP0 : (size_t)FN_ * (KP0 + KP1);
    const char* Bw = (const char*)(wfw + wfwoff + (size_t)n0c * (ntw * 64));
    const char* Bp = (const char*)(wfp + wfpoff + (size_t)n0c * (ntp * 64));
    const float* bias = ((conv == 0) ? cb3 : (conv == 1) ? cb4 : cb5) + n0c;
    const int M = 126 - conv;

    int t = threadIdx.x;
    int w = t >> 6, lane = t & 63;
    int wm = w & 1, wn = w >> 1;
    int l15 = lane & 15, lhi = lane >> 4;

#define STAGEB(BUF, T)                                                          \
    {                                                                           \
        int isw_ = (T) < ntw;                                                   \
        const char* base_ = isw_ ? Bw : Bp;                                     \
        size_t str_ = isw_ ? kwB : kpB;                                         \
        size_t kb_ = (size_t)(isw_ ? (T) : (T) - ntw) << 7;                     \
        _Pragma("unroll")                                                       \
        for (int u = 0; u < 4; ++u) {                                           \
            int ci = (u << 8) + t;                                              \
            int fr = ci >> 3, cin = ci & 7;                                     \
            int sc = cin ^ (fr & 7);                                            \
            gld_lds16(base_ + (size_t)fr * str_ + kb_ + ((size_t)sc << 4),      \
                      (char*)sB + (size_t)(BUF) * 16384 + (ci << 4));           \
        }                                                                       \
    }

#define LOADA(DST, T)                                                           \
    {                                                                           \
        int isw_ = (T) < ntw;                                                   \
        int kb_ = (isw_ ? (T) : (T) - ntw) << 6;                                \
        _Pragma("unroll")                                                       \
        for (int ks = 0; ks < 2; ++ks) {                                        \
            int kk = kb_ + (ks << 5) + (lhi << 3);                              \
            _Pragma("unroll")                                                   \
            for (int mf = 0; mf < 4; ++mf)                                      \
                DST[ks][mf] = *(const bf16x8*)((isw_ ? rowW[mf] : rowP[mf]) + kk); \
        }                                                                       \
    }

#define PHASE(KT, CUR, NXT)                                                     \
    {                                                                           \
        if ((KT) + 2 < nt) STAGEB(((KT) + 2) % 3, (KT) + 2);                    \
        if ((KT) + 1 < nt) LOADA(NXT, (KT) + 1);                                \
        WAITV12;                                                                \
        MEMFENCE; __builtin_amdgcn_s_barrier(); MEMFENCE;                       \
        const ushort_t* cB = &sB[(KT) % 3][0];                                  \
        _Pragma("unroll")                                                       \
        for (int ks = 0; ks < 2; ++ks) {                                        \
            bf16x8 bfr[4];                                                      \
            _Pragma("unroll")                                                   \
            for (int nf = 0; nf < 4; ++nf) {                                    \
                int fr = (wn << 6) + (nf << 4) + l15;                           \
                int pc = ((ks << 2) + lhi) ^ (fr & 7);                          \
                bfr[nf] = *(const bf16x8*)&cB[fr * 64 + pc * 8];                \
            }                                                                   \
            __builtin_amdgcn_s_setprio(1);                                      \
            _Pragma("unroll")                                                   \
            for (int mf = 0; mf < 4; ++mf)                                      \
                _Pragma("unroll")                                               \
                for (int nf = 0; nf < 4; ++nf)                                  \
                    acc[mf][nf] = __builtin_amdgcn_mfma_f32_16x16x32_bf16(      \
                        CUR[ks][mf], bfr[nf], acc[mf][nf], 0, 0, 0);            \
            __builtin_amdgcn_s_setprio(0);                                      \
        }                                                                       \
    }

    // ---- corr on VALU first (all its loads are consumed here -> vmcnt drains)
    {
        float we0[15];
#pragma unroll
        for (int j = 0; j < 15; ++j)
            we0[j] = bf2f(we_flat[(size_t)b * WE_SLAB + lane + (j << 6)]);
        const ushort_t* cwb = corrw + (size_t)conv * (FN_ * KC) + (size_t)n0c * KC;
        for (int fi = 0; fi < 32; ++fi) {
            int f = (w << 5) + fi;
            const ushort_t* cr = cwb + (size_t)f * KC + lane;
            float s = 0.f;
#pragma unroll
            for (int j = 0; j < 15; ++j) s += we0[j] * bf2f(cr[j << 6]);
#pragma unroll
            for (int off = 32; off; off >>= 1) s += __shfl_xor(s, off);
            if (lane == 0) corr_lds[f] = s;
        }
    }

    // per-mf A row base pointers (global, 16B-aligned rows)
    const ushort_t* rowW[4];
    const ushort_t* rowP[4];
#pragma unroll
    for (int mf = 0; mf < 4; ++mf) {
        int row = (wm << 6) + (mf << 4) + l15;
        rowW[mf] = we_flat + (size_t)b * WE_SLAB  + row * SW;
        rowP[mf] = posflat + (size_t)b * POS_SLAB + row * SP;
    }

    f32x4 acc[4][4] = {};
    bf16x8 afrA[2][4], afrB[2][4];

    STAGEB(0, 0);
    STAGEB(1, 1);
    LOADA(afrA, 0);

    for (int kt = 0; kt < nt; kt += 2) {
        PHASE(kt, afrA, afrB);
        if (kt + 1 < nt) PHASE(kt + 1, afrB, afrA);
    }
#undef PHASE
#undef LOADA
#undef STAGEB

    // ---- epilogue: row-0 corr subtract, masked max, bias+tanh ----
#pragma unroll
    for (int nf = 0; nf < 4; ++nf) {
        int col = (wn << 6) + (nf << 4) + l15;
        float bmax = -INFINITY;
#pragma unroll
        for (int mf = 0; mf < 4; ++mf) {
#pragma unroll
            for (int j = 0; j < 4; ++j) {
                int i = (wm << 6) + (mf << 4) + (lhi << 2) + j;
                float v = acc[mf][nf][j];
                if (i == 0) v -= corr_lds[col];
                if (i < M) bmax = fmaxf(bmax, v);
            }
        }
        bmax = fmaxf(bmax, __shfl_xor(bmax, 16));
        bmax = fmaxf(bmax, __shfl_xor(bmax, 32));
        if (lane < 16) red[wm][col] = bmax;
    }
    __syncthreads();
    if (t < 128) {
        float m = fmaxf(red[0][t], red[1][t]);
        sf[(size_t)b * (3 * FN_) + (conv << 8) + n0c + t] = tanhf(m + bias[t]);
    }
}

// ---- tail: span/lex feats + g + final logits, one block per b ----
__device__ __forceinline__ int tok_at(const int* inputs, int b, int idx) {
    return (idx >= 0 && idx < L_) ? inputs[b * L_ + idx] : 0;
}
__global__ __launch_bounds__(256) void tail_kernel(
    const int* __restrict__ inputs,
    const int* __restrict__ e1s, const int* __restrict__ e1e,
    const int* __restrict__ e2s, const int* __restrict__ e2e,
    const float* __restrict__ emb, const float* __restrict__ sf,
    const float* __restrict__ W1, const float* __restrict__ b1,
    const float* __restrict__ W2, const float* __restrict__ b2,
    float* __restrict__ y)
{
    __shared__ float o_loc[1900];
    __shared__ float sfl[3 * FN_];

    int b = blockIdx.x, t = threadIdx.x;
    int lane = t & 63, w = t >> 6;

    for (int k = t; k < 3 * FN_; k += 256) sfl[k] = sf[(size_t)b * (3 * FN_) + k];

    int s1 = e1s[b], t1 = e1e[b], s2 = e2s[b], t2 = e2e[b];
    float inv1 = 1.f / (float)(t1 - s1 + 1);
    float inv2 = 1.f / (float)(t2 - s2 + 1);
    int ta = tok_at(inputs, b, s1 - 1), tb = tok_at(inputs, b, t1 + 1);
    int tc = tok_at(inputs, b, s2 - 1), td = tok_at(inputs, b, t2 + 1);
    for (int d = t; d < E_; d += 256) {
        float s = 0.f;
        for (int p = s1; p <= t1; ++p) s += emb[(size_t)tok_at(inputs, b, p) * E_ + d];
        o_loc[d] = s * inv1;
        s = 0.f;
        for (int p = s2; p <= t2; ++p) s += emb[(size_t)tok_at(inputs, b, p) * E_ + d];
        o_loc[E_ + d] = s * inv2;
        o_loc[2 * E_ + d] = emb[(size_t)ta * E_ + d];
        o_loc[3 * E_ + d] = emb[(size_t)tb * E_ + d];
        o_loc[4 * E_ + d] = emb[(size_t)tc * E_ + d];
        o_loc[5 * E_ + d] = emb[(size_t)td * E_ + d];
    }
    __syncthreads();

    for (int h = w; h < H2_; h += 4) {
        const float* wr = W1 + (size_t)h * (3 * FN_);
        float acc = 0.f;
#pragma unroll
        for (int j = 0; j < 12; ++j) acc += sfl[lane + (j << 6)] * wr[lane + (j << 6)];
        for (int off = 32; off; off >>= 1) acc += __shfl_down(acc, off);
        if (lane == 0) o_loc[1800 + h] = tanhf(acc + b1[h]);
    }
    __syncthreads();

    for (int lab = w; lab < LAB_; lab += 4) {
        const float* wr = W2 + (size_t)lab * 1900;
        float acc = 0.f;
        for (int d = lane; d < 1900; d += 64) acc += o_loc[d] * wr[d];
        for (int off = 32; off; off >>= 1) acc += __shfl_down(acc, off);
        if (lane == 0) y[(size_t)b * LAB_ + lab] = acc + b2[lab];
    }
}

extern "C" void kernel_launch(void* const* d_in, const int* in_sizes, int n_in,
                              void* d_out, int out_size, void* d_ws, size_t ws_size,
                              hipStream_t stream) {
    const int*   inputs = (const int*)d_in[0];
    const int*   e1s    = (const int*)d_in[1];
    const int*   e1e    = (const int*)d_in[2];
    const int*   e2s    = (const int*)d_in[3];
    const int*   e2e    = (const int*)d_in[4];
    const int*   p1     = (const int*)d_in[5];
    const int*   p2     = (const int*)d_in[6];
    const float* emb    = (const float*)d_in[7];
    const float* pos1   = (const float*)d_in[8];
    const float* pos2   = (const float*)d_in[9];
    const float* w3     = (const float*)d_in[10];
    const float* cb3    = (const float*)d_in[11];
    const float* w4     = (const float*)d_in[12];
    const float* cb4    = (const float*)d_in[13];
    const float* w5     = (const float*)d_in[14];
    const float* cb5    = (const float*)d_in[15];
    const float* W1     = (const float*)d_in[16];
    const float* b1     = (const float*)d_in[17];
    const float* W2     = (const float*)d_in[18];
    const float* b2     = (const float*)d_in[19];
    float* y = (float*)d_out;

    char* ws = (char*)d_ws;
    size_t off = 0;
    ushort_t* we_flat = (ushort_t*)(ws + off); off += (size_t)N_WE * 2;
    ushort_t* posflat = (ushort_t*)(ws + off); off += (size_t)N_POSF * 2;
    ushort_t* wfw     = (ushort_t*)(ws + off); off += (size_t)N_WFW * 2;
    ushort_t* wfp     = (ushort_t*)(ws + off); off += (size_t)N_WFP * 2;
    ushort_t* corrw   = (ushort_t*)(ws + off); off += (size_t)N_CORR * 2;
    float*    sf      = (float*)(ws + off);    off += (size_t)B_ * 3 * FN_ * 4;

    setup_kernel<<<dim3(SETUP_BLOCKS), dim3(256), 0, stream>>>(
        inputs, p1, p2, emb, pos1, pos2, w3, w4, w5,
        we_flat, posflat, wfw, wfp, corrw);

    conv_fold<<<dim3(B_, 3, 2), dim3(256), 0, stream>>>(
        we_flat, posflat, wfw, wfp, corrw, cb3, cb4, cb5, sf);

    tail_kernel<<<dim3(B_), dim3(256), 0, stream>>>(
        inputs, e1s, e1e, e2s, e2e, emb, sf, W1, b1, W2, b2, y);
}